// Round 12
// baseline (126.939 us; speedup 1.0000x reference)
//
#include <hip/hip_runtime.h>
#include <stdint.h>

typedef unsigned short u16;
typedef __attribute__((ext_vector_type(8))) short short8;
typedef __attribute__((ext_vector_type(4))) float f32x4;

#define S_LEN 2048
#define HID   1024
#define QKV_LD 3072
#define M_ROWS 8192   // B*S

__device__ __forceinline__ u16 f2bf(float f) {
  unsigned u = __float_as_uint(f);
  unsigned r = (u + 0x7fffu + ((u >> 16) & 1u)) >> 16;
  return (u16)r;
}

__device__ __forceinline__ void gload16(const u16* g, u16* l) {
  __builtin_amdgcn_global_load_lds(
      (const __attribute__((address_space(1))) unsigned int*)(g),
      (__attribute__((address_space(3))) unsigned int*)(l),
      16, 0, 0);
}

__device__ __forceinline__ void wgbar() {
  asm volatile("" ::: "memory");
  __builtin_amdgcn_s_barrier();
  asm volatile("" ::: "memory");
}

// -------- fused prep: cvt x->bf16, pack biases, transpose 4 weights --------
__global__ __launch_bounds__(256) void prep(
    const float* __restrict__ x, u16* __restrict__ xb,
    const float* __restrict__ bq, const float* __restrict__ bk,
    const float* __restrict__ bv, float* __restrict__ bqkv,
    const float* __restrict__ Wq, const float* __restrict__ Wk,
    const float* __restrict__ Wv, const float* __restrict__ Wo,
    u16* __restrict__ wqkvt, u16* __restrict__ wot) {
  __shared__ float tile[32][33];
  const int bid = blockIdx.x;
  if (bid < 4096) {                      // x: f32 -> bf16, 8 elem/thread
    int i = (bid * 256 + threadIdx.x) * 8;
    float4 a = *(const float4*)(x + i);
    float4 b = *(const float4*)(x + i + 4);
    u16 t[8];
    t[0] = f2bf(a.x); t[1] = f2bf(a.y); t[2] = f2bf(a.z); t[3] = f2bf(a.w);
    t[4] = f2bf(b.x); t[5] = f2bf(b.y); t[6] = f2bf(b.z); t[7] = f2bf(b.w);
    *(short8*)(xb + i) = *(short8*)t;
    return;
  }
  if (bid == 4096) {                     // bias pack
    for (int i = threadIdx.x; i < 3072; i += 256)
      bqkv[i] = (i < 1024) ? bq[i] : (i < 2048) ? bk[i - 1024] : bv[i - 2048];
    return;
  }
  const int wid = bid - 4097;            // weight transpose: f32[K][N]->bf16[N][K]
  const int z = wid >> 10, rem = wid & 1023;
  const float* in = (z == 0) ? Wq : (z == 1) ? Wk : (z == 2) ? Wv : Wo;
  u16* out = (z < 3) ? (wqkvt + (size_t)z * 1024 * 1024) : wot;
  int tx = threadIdx.x & 31, ty = threadIdx.x >> 5;
  int n0 = (rem & 31) * 32, k0 = (rem >> 5) * 32;
#pragma unroll
  for (int i = 0; i < 32; i += 8)
    tile[ty + i][tx] = in[(size_t)(k0 + ty + i) * 1024 + n0 + tx];
  __syncthreads();
#pragma unroll
  for (int i = 0; i < 32; i += 8)
    out[(size_t)(n0 + ty + i) * 1024 + k0 + tx] = f2bf(tile[tx][ty + i]);
}

// ---------------- GEMM1: 3-phase ring-2 + L2 super-tile (r11 best) --------
// C[8192,3072] = A * Bt^T + bias (bf16 out).  BM=128 x BN=192, BK=64,
// 4 waves (2M x 2N), per-wave 64x96.  Ring-2 x 40 KiB = 80 KiB -> 2
// blocks/CU.  Grid 1024 = 2.0 tail-free rounds.  Super-tile XCD map:
// each XCD owns 16bm x 8bn (working set ~L2) — FETCH 85->44 MB (r11).
// 3 phases x 16 MFMA, staging P1:B{2..5}(t+1) / P2:A(t+2) / P3:B{0,1}(t+2),
// one vmcnt(6) gate per tile.  XOR slot swizzle (0 conflicts, r1-r11).
// NEW (r12): nontemporal C stores — C streams past L2 so the epilogue
// does not evict the super-tile's resident A/B panels.
__global__ __launch_bounds__(256, 2) void gemm_k1(
    const u16* __restrict__ A, const u16* __restrict__ Bt,
    const float* __restrict__ bias, u16* __restrict__ C) {
  constexpr int K = 1024, NT = 16, N = 3072;
  constexpr int AU = 128 * 64;              // 8192 u16
  constexpr int BUF = 320 * 64;             // 20480 u16 (40 KiB)
  __shared__ __align__(16) u16 smem[2 * BUF];

  const int tid = threadIdx.x;
  const int wave = tid >> 6, lane = tid & 63;
  const int qlane = lane & 15, kgrp = lane >> 4;
  const int wm = wave >> 1, wn = wave & 1;
  const int wg = blockIdx.x;
  const int xcd = wg & 7, local = wg >> 3;   // 128 blocks per XCD
  const int bm = (xcd >> 1) * 16 + (local >> 3);   // 64 bm rows
  const int bn = (xcd & 1) * 8 + (local & 7);      // 16 bn cols

  // staging: unit = 32 rows x 64 cols (4 KiB = 256 thr x 16 B)
  const int srow = tid >> 3;                // 0..31
  const int sslot = tid & 7;
  uint32_t gA[4], gB[6];
#pragma unroll
  for (int au = 0; au < 4; ++au) {
    int row = au * 32 + srow;
    gA[au] = (uint32_t)((bm * 128 + row) * K + ((sslot ^ (row & 7)) * 8));
  }
#pragma unroll
  for (int bu = 0; bu < 6; ++bu) {
    int row = bu * 32 + srow;
    gB[bu] = (uint32_t)((bn * 192 + row) * K + ((sslot ^ (row & 7)) * 8));
  }

  auto stgA = [&](int t, int au) {
    gload16(A + (size_t)gA[au] + t * 64, &smem[(t & 1) * BUF + au * 2048 + tid * 8]);
  };
  auto stgB = [&](int t, int bu) {
    gload16(Bt + (size_t)gB[bu] + t * 64, &smem[(t & 1) * BUF + AU + bu * 2048 + tid * 8]);
  };

  // prologue: tile0 (10 units), A(1) (4), B-c0(1) (2) = 16 loads
#pragma unroll
  for (int au = 0; au < 4; ++au) stgA(0, au);
#pragma unroll
  for (int bu = 0; bu < 6; ++bu) stgB(0, bu);
#pragma unroll
  for (int au = 0; au < 4; ++au) stgA(1, au);
  stgB(1, 0); stgB(1, 1);
  asm volatile("s_waitcnt vmcnt(6)" ::: "memory");   // tile 0 landed
  wgbar();

  f32x4 acc[4][6] = {};
  short8 af[4][2], bf[2][2];

  for (int t = 0; t < NT; ++t) {
    const u16* bp = &smem[(t & 1) * BUF];

    // ---- P1: read A (8) + B nf0-1 (4); stage B-c1,c2(t+1) ----
#pragma unroll
    for (int mf = 0; mf < 4; ++mf)
#pragma unroll
      for (int kk = 0; kk < 2; ++kk) {
        int r = wm * 64 + mf * 16 + qlane;
        af[mf][kk] = *(const short8*)&bp[r * 64 + ((kk * 4 + kgrp) ^ (r & 7)) * 8];
      }
#pragma unroll
    for (int nf = 0; nf < 2; ++nf)
#pragma unroll
      for (int kk = 0; kk < 2; ++kk) {
        int r = wn * 96 + nf * 16 + qlane;
        bf[nf][kk] = *(const short8*)&bp[AU + r * 64 + ((kk * 4 + kgrp) ^ (r & 7)) * 8];
      }
    if (t + 1 < NT) { stgB(t + 1, 2); stgB(t + 1, 3); stgB(t + 1, 4); stgB(t + 1, 5); }
    wgbar();
    asm volatile("s_waitcnt lgkmcnt(0)" ::: "memory");
    __builtin_amdgcn_s_setprio(1);
#pragma unroll
    for (int mf = 0; mf < 4; ++mf)
#pragma unroll
      for (int nf = 0; nf < 2; ++nf)
#pragma unroll
        for (int kk = 0; kk < 2; ++kk)
          acc[mf][nf] = __builtin_amdgcn_mfma_f32_16x16x32_bf16(
              af[mf][kk], bf[nf][kk], acc[mf][nf], 0, 0, 0);
    __builtin_amdgcn_s_setprio(0);
    wgbar();

    // ---- P2: read B nf2-3 (4); stage A(t+2) ----
#pragma unroll
    for (int nf = 0; nf < 2; ++nf)
#pragma unroll
      for (int kk = 0; kk < 2; ++kk) {
        int r = wn * 96 + (nf + 2) * 16 + qlane;
        bf[nf][kk] = *(const short8*)&bp[AU + r * 64 + ((kk * 4 + kgrp) ^ (r & 7)) * 8];
      }
    if (t + 2 < NT) { stgA(t + 2, 0); stgA(t + 2, 1); stgA(t + 2, 2); stgA(t + 2, 3); }
    wgbar();
    asm volatile("s_waitcnt lgkmcnt(0)" ::: "memory");
    __builtin_amdgcn_s_setprio(1);
#pragma unroll
    for (int mf = 0; mf < 4; ++mf)
#pragma unroll
      for (int nf = 0; nf < 2; ++nf)
#pragma unroll
        for (int kk = 0; kk < 2; ++kk)
          acc[mf][nf + 2] = __builtin_amdgcn_mfma_f32_16x16x32_bf16(
              af[mf][kk], bf[nf][kk], acc[mf][nf + 2], 0, 0, 0);
    __builtin_amdgcn_s_setprio(0);
    wgbar();

    // ---- P3: read B nf4-5 (4); stage B-c0(t+2); gate vmcnt ----
#pragma unroll
    for (int nf = 0; nf < 2; ++nf)
#pragma unroll
      for (int kk = 0; kk < 2; ++kk) {
        int r = wn * 96 + (nf + 4) * 16 + qlane;
        bf[nf][kk] = *(const short8*)&bp[AU + r * 64 + ((kk * 4 + kgrp) ^ (r & 7)) * 8];
      }
    if (t + 2 < NT) { stgB(t + 2, 0); stgB(t + 2, 1); }
    wgbar();
    asm volatile("s_waitcnt lgkmcnt(0)" ::: "memory");
    __builtin_amdgcn_s_setprio(1);
#pragma unroll
    for (int mf = 0; mf < 4; ++mf)
#pragma unroll
      for (int nf = 0; nf < 2; ++nf)
#pragma unroll
        for (int kk = 0; kk < 2; ++kk)
          acc[mf][nf + 4] = __builtin_amdgcn_mfma_f32_16x16x32_bf16(
              af[mf][kk], bf[nf][kk], acc[mf][nf + 4], 0, 0, 0);
    __builtin_amdgcn_s_setprio(0);
    if (t + 2 < NT)      asm volatile("s_waitcnt vmcnt(6)" ::: "memory");
    else if (t + 1 < NT) asm volatile("s_waitcnt vmcnt(0)" ::: "memory");
    if (t + 1 < NT) wgbar();
  }

  // epilogue (nontemporal: don't evict resident A/B panels from L2)
#pragma unroll
  for (int nf = 0; nf < 6; ++nf) {
    int col = bn * 192 + wn * 96 + nf * 16 + qlane;
    float bv = bias[col];
#pragma unroll
    for (int mf = 0; mf < 4; ++mf) {
      int row0 = bm * 128 + wm * 64 + mf * 16 + kgrp * 4;
#pragma unroll
      for (int r = 0; r < 4; ++r)
        __builtin_nontemporal_store(f2bf(acc[mf][nf][r] + bv),
                                    &C[(size_t)(row0 + r) * N + col]);
    }
  }
}

// ---------------- GEMM2: 2-phase ring-2 + super-tile (r11) + nt stores ----
__global__ __launch_bounds__(256, 2) void gemm_k2(
    const u16* __restrict__ A, const u16* __restrict__ Bt,
    const float* __restrict__ bias, float* __restrict__ C) {
  constexpr int K = 1024, NT = 16, N = 1024;
  constexpr int AU = 128 * 64;            // 8192 u16
  constexpr int SLAB = 256 * 64;          // 16384 u16 (32 KiB)
  __shared__ __align__(16) u16 smem[2 * SLAB];

  const int tid = threadIdx.x;
  const int wave = tid >> 6, lane = tid & 63;
  const int qlane = lane & 15, kgrp = lane >> 4;
  const int wm = wave >> 1, wn = wave & 1;
  const int wg = blockIdx.x;
  const int xcd = wg & 7, local = wg >> 3;   // 64 blocks per XCD
  const int bm = (xcd >> 1) * 16 + (local >> 2);   // 64 bm rows
  const int bn = (xcd & 1) * 4 + (local & 3);      // 8 bn cols

  const int srow = tid >> 3;
  const int sslot = (tid & 7) ^ (srow & 7);
  uint32_t gA[4], gB[4];
#pragma unroll
  for (int u = 0; u < 4; ++u) {
    gA[u] = (uint32_t)((bm * 128 + u * 32 + srow) * K + sslot * 8);
    gB[u] = (uint32_t)((bn * 128 + u * 32 + srow) * K + sslot * 8);
  }
  auto stgA = [&](int t, int u) {
    gload16(A + (size_t)gA[u] + t * 64, &smem[(t & 1) * SLAB + u * 2048 + tid * 8]);
  };
  auto stgB = [&](int t, int u) {
    gload16(Bt + (size_t)gB[u] + t * 64, &smem[(t & 1) * SLAB + AU + u * 2048 + tid * 8]);
  };

  int aaddr[4], baddr[4];
#pragma unroll
  for (int f = 0; f < 4; ++f) {
    aaddr[f] = (wm * 64 + f * 16 + qlane) * 64;
    baddr[f] = AU + (wn * 64 + f * 16 + qlane) * 64;
  }
  const int arow7 = (wm * 64 + qlane) & 7;
  const int brow7 = (wn * 64 + qlane) & 7;

  f32x4 acc[4][4] = {};
  short8 af[4][2], bf[2][2];

#pragma unroll
  for (int u = 0; u < 4; ++u) stgA(0, u);
#pragma unroll
  for (int u = 0; u < 4; ++u) stgB(0, u);
#pragma unroll
  for (int u = 0; u < 4; ++u) stgA(1, u);
  stgB(1, 0); stgB(1, 2);
  asm volatile("s_waitcnt vmcnt(6)" ::: "memory");
  wgbar();

  for (int t = 0; t < NT; ++t) {
    const u16* bp = &smem[(t & 1) * SLAB];

    // ---- P1 ----
#pragma unroll
    for (int mf = 0; mf < 4; ++mf)
#pragma unroll
      for (int kk = 0; kk < 2; ++kk)
        af[mf][kk] = *(const short8*)&bp[aaddr[mf] + (((kk * 4 + kgrp) ^ arow7) * 8)];
#pragma unroll
    for (int nf = 0; nf < 2; ++nf)
#pragma unroll
      for (int kk = 0; kk < 2; ++kk)
        bf[nf][kk] = *(const short8*)&bp[baddr[nf] + (((kk * 4 + kgrp) ^ brow7) * 8)];
    if (t + 1 < NT) { stgB(t + 1, 1); stgB(t + 1, 3); }
    wgbar();
    asm volatile("s_waitcnt lgkmcnt(0)" ::: "memory");
    __builtin_amdgcn_s_setprio(1);
#pragma unroll
    for (int mf = 0; mf < 4; ++mf)
#pragma unroll
      for (int nf = 0; nf < 2; ++nf)
#pragma unroll
        for (int kk = 0; kk < 2; ++kk)
          acc[mf][nf] = __builtin_amdgcn_mfma_f32_16x16x32_bf16(
              af[mf][kk], bf[nf][kk], acc[mf][nf], 0, 0, 0);
    __builtin_amdgcn_s_setprio(0);
    wgbar();

    // ---- P2 ----
#pragma unroll
    for (int nf = 0; nf < 2; ++nf)
#pragma unroll
      for (int kk = 0; kk < 2; ++kk)
        bf[nf][kk] = *(const short8*)&bp[baddr[nf + 2] + (((kk * 4 + kgrp) ^ brow7) * 8)];
    if (t + 2 < NT) {
      stgA(t + 2, 0); stgA(t + 2, 1); stgA(t + 2, 2); stgA(t + 2, 3);
      stgB(t + 2, 0); stgB(t + 2, 2);
    }
    wgbar();
    asm volatile("s_waitcnt lgkmcnt(0)" ::: "memory");
    __builtin_amdgcn_s_setprio(1);
#pragma unroll
    for (int mf = 0; mf < 4; ++mf)
#pragma unroll
      for (int nf = 0; nf < 2; ++nf)
#pragma unroll
        for (int kk = 0; kk < 2; ++kk)
          acc[mf][nf + 2] = __builtin_amdgcn_mfma_f32_16x16x32_bf16(
              af[mf][kk], bf[nf][kk], acc[mf][nf + 2], 0, 0, 0);
    __builtin_amdgcn_s_setprio(0);
    if (t + 2 < NT)      asm volatile("s_waitcnt vmcnt(6)" ::: "memory");
    else if (t + 1 < NT) asm volatile("s_waitcnt vmcnt(0)" ::: "memory");
    if (t + 1 < NT) wgbar();
  }

#pragma unroll
  for (int nf = 0; nf < 4; ++nf) {
    int col = bn * 128 + wn * 64 + nf * 16 + qlane;
    float bv = bias[col];
#pragma unroll
    for (int mf = 0; mf < 4; ++mf) {
      int row0 = bm * 128 + wm * 64 + mf * 16 + kgrp * 4;
#pragma unroll
      for (int r = 0; r < 4; ++r)
        __builtin_nontemporal_store(acc[mf][nf][r] + bv,
                                    &C[(size_t)(row0 + r) * N + col]);
    }
  }
}

// ---------------- banded local attention (round-9, XCD-clustered) ---------
__global__ __launch_bounds__(256, 2) void attn_local(
    const u16* __restrict__ qkv, const int* __restrict__ amask,
    u16* __restrict__ aout) {
  __shared__ __align__(16) u16 Kl[192][72];
  __shared__ __align__(16) u16 Vt[64][200];
  __shared__ __align__(16) u16 Pl[4][32][104];

  const int tid = threadIdx.x, wave = tid >> 6, lane = tid & 63;
  const int qlane = lane & 15, kgrp = lane >> 4;
  const int rbz = blockIdx.x;
  const int bz = (rbz & 7) * 128 + (rbz >> 3);
  const int qt = bz & 15, h = (bz >> 4) & 15, b = bz >> 8;
  const int qs0 = qt * 128;
  const int jt = qs0 - 32;
  const size_t rbase = (size_t)b * S_LEN;

  {
    const int r0 = tid >> 3, c0 = (tid & 7) * 8;
#pragma unroll
    for (int p = 0; p < 6; ++p) {
      int row = p * 32 + r0;
      int j = jt + row;
      u16 kv[8], vv[8];
      if (j >= 0 && j < S_LEN) {
        const u16* kp = qkv + (rbase + j) * QKV_LD + HID + h * 64 + c0;
        *(short8*)kv = *(const short8*)kp;
        *(short8*)vv = *(const short8*)(kp + HID);
      } else {
#pragma unroll
        for (int q = 0; q < 8; ++q) { kv[q] = 0; vv[q] = 0; }
      }
      *(short8*)&Kl[row][c0] = *(short8*)kv;
#pragma unroll
      for (int q = 0; q < 8; ++q) Vt[c0 + q][row] = vv[q];
    }
  }

  short8 qf[2][2];
#pragma unroll
  for (int mf = 0; mf < 2; ++mf)
#pragma unroll
    for (int kk = 0; kk < 2; ++kk)
      qf[mf][kk] = *(const short8*)(qkv +
          (rbase + qs0 + wave * 32 + mf * 16 + qlane) * QKV_LD +
          h * 64 + kk * 32 + kgrp * 8);

  __syncthreads();

  f32x4 sc[2][6] = {};
#pragma unroll
  for (int kk = 0; kk < 2; ++kk) {
    short8 kf[6];
#pragma unroll
    for (int nf = 0; nf < 6; ++nf)
      kf[nf] = *(const short8*)&Kl[wave * 32 + nf * 16 + qlane][kk * 32 + kgrp * 8];
#pragma unroll
    for (int mf = 0; mf < 2; ++mf)
#pragma unroll
      for (int nf = 0; nf < 6; ++nf)
        sc[mf][nf] = __builtin_amdgcn_mfma_f32_16x16x32_bf16(
            qf[mf][kk], kf[nf], sc[mf][nf], 0, 0, 0);
  }

  int jcol[6], mv[6];
#pragma unroll
  for (int nf = 0; nf < 6; ++nf) {
    int j = jt + wave * 32 + nf * 16 + qlane;
    jcol[nf] = j;
    mv[nf] = (j >= 0 && j < S_LEN) ? amask[rbase + j] : 0;
  }

  float inv[2][4];
#pragma unroll
  for (int mf = 0; mf < 2; ++mf) {
    const int irow0 = qs0 + wave * 32 + mf * 16 + kgrp * 4;
    float mx[4] = {-1e30f, -1e30f, -1e30f, -1e30f};
#pragma unroll
    for (int r = 0; r < 4; ++r) {
      int i = irow0 + r;
#pragma unroll
      for (int nf = 0; nf < 6; ++nf) {
        int d = i - jcol[nf];
        if (mv[nf] && d >= -32 && d <= 32) mx[r] = fmaxf(mx[r], sc[mf][nf][r]);
      }
    }
#pragma unroll
    for (int m = 1; m < 16; m <<= 1)
#pragma unroll
      for (int r = 0; r < 4; ++r)
        mx[r] = fmaxf(mx[r], __shfl_xor(mx[r], m));
    float sm[4] = {0.f, 0.f, 0.f, 0.f};
#pragma unroll
    for (int r = 0; r < 4; ++r) {
      int i = irow0 + r;
#pragma unroll
      for (int nf = 0; nf < 6; ++nf) {
        int d = i - jcol[nf];
        bool val = mv[nf] && d >= -32 && d <= 32;
        float p = val ? __expf((sc[mf][nf][r] - mx[r]) * 0.125f) : 0.f;
        sc[mf][nf][r] = p;
        sm[r] += p;
      }
    }
#pragma unroll
    for (int m = 1; m < 16; m <<= 1)
#pragma unroll
      for (int r = 0; r < 4; ++r)
        sm[r] += __shfl_xor(sm[r], m);
#pragma unroll
    for (int r = 0; r < 4; ++r)
      inv[mf][r] = sm[r] > 0.f ? 1.f / sm[r] : 0.f;
#pragma unroll
    for (int nf = 0; nf < 6; ++nf)
#pragma unroll
      for (int r = 0; r < 4; ++r)
        Pl[wave][mf * 16 + kgrp * 4 + r][nf * 16 + qlane] = f2bf(sc[mf][nf][r]);
  }
  __syncthreads();

  f32x4 oc[2][4] = {};
#pragma unroll
  for (int ks = 0; ks < 3; ++ks) {
    short8 pa[2], vb[4];
#pragma unroll
    for (int mf = 0; mf < 2; ++mf)
      pa[mf] = *(const short8*)&Pl[wave][mf * 16 + qlane][ks * 32 + kgrp * 8];
#pragma unroll
    for (int nf = 0; nf < 4; ++nf)
      vb[nf] = *(const short8*)&Vt[nf * 16 + qlane][wave * 32 + ks * 32 + kgrp * 8];
#pragma unroll
    for (int mf = 0; mf < 2; ++mf)
#pragma unroll
      for (int nf = 0; nf < 4; ++nf)
        oc[mf][nf] = __builtin_amdgcn_mfma_f32_16x16x32_bf16(
            pa[mf], vb[nf], oc[mf][nf], 0, 0, 0);
  }

#pragma unroll
  for (int mf = 0; mf < 2; ++mf)
#pragma unroll
    for (int nf = 0; nf < 4; ++nf)
#pragma unroll
      for (int r = 0; r < 4; ++r) {
        size_t row = rbase + qs0 + wave * 32 + mf * 16 + kgrp * 4 + r;
        aout[row * HID + h * 64 + nf * 16 + qlane] =
            f2bf(oc[mf][nf][r] * inv[mf][r]);
      }
}

// ---------------- launch ----------------
extern "C" void kernel_launch(void* const* d_in, const int* in_sizes, int n_in,
                              void* d_out, int out_size, void* d_ws, size_t ws_size,
                              hipStream_t stream) {
  const float* x  = (const float*)d_in[0];
  const int* amask = (const int*)d_in[1];
  const float* Wq = (const float*)d_in[2];
  const float* bq = (const float*)d_in[3];
  const float* Wk = (const float*)d_in[4];
  const float* bk = (const float*)d_in[5];
  const float* Wv = (const float*)d_in[6];
  const float* bv = (const float*)d_in[7];
  const float* Wo = (const float*)d_in[8];
  const float* bo = (const float*)d_in[9];
  float* out = (float*)d_out;

  char* w = (char*)d_ws;
  u16* xb    = (u16*)w;   w += (size_t)M_ROWS * HID * 2;
  u16* wqkvt = (u16*)w;   w += (size_t)3072 * 1024 * 2;
  u16* wot   = (u16*)w;   w += (size_t)1024 * 1024 * 2;
  float* bqkv = (float*)w; w += 3072 * 4 + 256;
  u16* qkv   = (u16*)w;   w += (size_t)M_ROWS * 3072 * 2;
  u16* aout  = (u16*)w;   w += (size_t)M_ROWS * HID * 2;

  prep<<<8193, 256, 0, stream>>>(x, xb, bq, bk, bv, bqkv,
                                 Wq, Wk, Wv, Wo, wqkvt, wot);
  gemm_k1<<<1024, 256, 0, stream>>>(xb, wqkvt, bqkv, qkv);
  attn_local<<<1024, 256, 0, stream>>>(qkv, amask, aout);
  gemm_k2<<<512, 256, 0, stream>>>(aout, wot, bo, out);
}

// Round 13
// 109.906 us; speedup vs baseline: 1.1550x; 1.1550x over previous
//
#include <hip/hip_runtime.h>
#include <stdint.h>

typedef unsigned short u16;
typedef __attribute__((ext_vector_type(8))) short short8;
typedef __attribute__((ext_vector_type(4))) float f32x4;

#define S_LEN 2048
#define HID   1024
#define QKV_LD 3072
#define M_ROWS 8192   // B*S

__device__ __forceinline__ u16 f2bf(float f) {
  unsigned u = __float_as_uint(f);
  unsigned r = (u + 0x7fffu + ((u >> 16) & 1u)) >> 16;
  return (u16)r;
}

__device__ __forceinline__ void gload16(const u16* g, u16* l) {
  __builtin_amdgcn_global_load_lds(
      (const __attribute__((address_space(1))) unsigned int*)(g),
      (__attribute__((address_space(3))) unsigned int*)(l),
      16, 0, 0);
}

__device__ __forceinline__ void wgbar() {
  asm volatile("" ::: "memory");
  __builtin_amdgcn_s_barrier();
  asm volatile("" ::: "memory");
}

// -------- fused prep: cvt x->bf16, pack biases, transpose 4 weights --------
__global__ __launch_bounds__(256) void prep(
    const float* __restrict__ x, u16* __restrict__ xb,
    const float* __restrict__ bq, const float* __restrict__ bk,
    const float* __restrict__ bv, float* __restrict__ bqkv,
    const float* __restrict__ Wq, const float* __restrict__ Wk,
    const float* __restrict__ Wv, const float* __restrict__ Wo,
    u16* __restrict__ wqkvt, u16* __restrict__ wot) {
  __shared__ float tile[32][33];
  const int bid = blockIdx.x;
  if (bid < 4096) {                      // x: f32 -> bf16, 8 elem/thread
    int i = (bid * 256 + threadIdx.x) * 8;
    float4 a = *(const float4*)(x + i);
    float4 b = *(const float4*)(x + i + 4);
    u16 t[8];
    t[0] = f2bf(a.x); t[1] = f2bf(a.y); t[2] = f2bf(a.z); t[3] = f2bf(a.w);
    t[4] = f2bf(b.x); t[5] = f2bf(b.y); t[6] = f2bf(b.z); t[7] = f2bf(b.w);
    *(short8*)(xb + i) = *(short8*)t;
    return;
  }
  if (bid == 4096) {                     // bias pack
    for (int i = threadIdx.x; i < 3072; i += 256)
      bqkv[i] = (i < 1024) ? bq[i] : (i < 2048) ? bk[i - 1024] : bv[i - 2048];
    return;
  }
  const int wid = bid - 4097;            // weight transpose: f32[K][N]->bf16[N][K]
  const int z = wid >> 10, rem = wid & 1023;
  const float* in = (z == 0) ? Wq : (z == 1) ? Wk : (z == 2) ? Wv : Wo;
  u16* out = (z < 3) ? (wqkvt + (size_t)z * 1024 * 1024) : wot;
  int tx = threadIdx.x & 31, ty = threadIdx.x >> 5;
  int n0 = (rem & 31) * 32, k0 = (rem >> 5) * 32;
#pragma unroll
  for (int i = 0; i < 32; i += 8)
    tile[ty + i][tx] = in[(size_t)(k0 + ty + i) * 1024 + n0 + tx];
  __syncthreads();
#pragma unroll
  for (int i = 0; i < 32; i += 8)
    out[(size_t)(n0 + ty + i) * 1024 + k0 + tx] = f2bf(tile[tx][ty + i]);
}

// ---------------- GEMM1: 3-phase ring-2 + L2 super-tile (r11 best) --------
// C[8192,3072] = A * Bt^T + bias (bf16 out).  BM=128 x BN=192, BK=64,
// 4 waves (2M x 2N), per-wave 64x96.  Ring-2 x 40 KiB = 80 KiB -> 2
// blocks/CU.  Grid 1024 = 2.0 tail-free rounds.  Super-tile XCD map:
// each XCD owns 16bm x 8bn (working set ~L2) — FETCH 85->44 MB, 54->52 us.
// 3 phases x 16 MFMA, staging P1:B{2..5}(t+1) / P2:A(t+2) / P3:B{0,1}(t+2),
// one vmcnt(6) gate per tile.  XOR slot swizzle (0 conflicts, r1-r11).
// (r12 nt-stores REVERTED: bypassing L2 defeats write-combining of 2-byte
//  bf16 lane stores -> WRITE_SIZE +50%, dur 52->66 us.)
__global__ __launch_bounds__(256, 2) void gemm_k1(
    const u16* __restrict__ A, const u16* __restrict__ Bt,
    const float* __restrict__ bias, u16* __restrict__ C) {
  constexpr int K = 1024, NT = 16, N = 3072;
  constexpr int AU = 128 * 64;              // 8192 u16
  constexpr int BUF = 320 * 64;             // 20480 u16 (40 KiB)
  __shared__ __align__(16) u16 smem[2 * BUF];

  const int tid = threadIdx.x;
  const int wave = tid >> 6, lane = tid & 63;
  const int qlane = lane & 15, kgrp = lane >> 4;
  const int wm = wave >> 1, wn = wave & 1;
  const int wg = blockIdx.x;
  const int xcd = wg & 7, local = wg >> 3;   // 128 blocks per XCD
  const int bm = (xcd >> 1) * 16 + (local >> 3);   // 64 bm rows
  const int bn = (xcd & 1) * 8 + (local & 7);      // 16 bn cols

  // staging: unit = 32 rows x 64 cols (4 KiB = 256 thr x 16 B)
  const int srow = tid >> 3;                // 0..31
  const int sslot = tid & 7;
  uint32_t gA[4], gB[6];
#pragma unroll
  for (int au = 0; au < 4; ++au) {
    int row = au * 32 + srow;
    gA[au] = (uint32_t)((bm * 128 + row) * K + ((sslot ^ (row & 7)) * 8));
  }
#pragma unroll
  for (int bu = 0; bu < 6; ++bu) {
    int row = bu * 32 + srow;
    gB[bu] = (uint32_t)((bn * 192 + row) * K + ((sslot ^ (row & 7)) * 8));
  }

  auto stgA = [&](int t, int au) {
    gload16(A + (size_t)gA[au] + t * 64, &smem[(t & 1) * BUF + au * 2048 + tid * 8]);
  };
  auto stgB = [&](int t, int bu) {
    gload16(Bt + (size_t)gB[bu] + t * 64, &smem[(t & 1) * BUF + AU + bu * 2048 + tid * 8]);
  };

  // prologue: tile0 (10 units), A(1) (4), B-c0(1) (2) = 16 loads
#pragma unroll
  for (int au = 0; au < 4; ++au) stgA(0, au);
#pragma unroll
  for (int bu = 0; bu < 6; ++bu) stgB(0, bu);
#pragma unroll
  for (int au = 0; au < 4; ++au) stgA(1, au);
  stgB(1, 0); stgB(1, 1);
  asm volatile("s_waitcnt vmcnt(6)" ::: "memory");   // tile 0 landed
  wgbar();

  f32x4 acc[4][6] = {};
  short8 af[4][2], bf[2][2];

  for (int t = 0; t < NT; ++t) {
    const u16* bp = &smem[(t & 1) * BUF];

    // ---- P1: read A (8) + B nf0-1 (4); stage B-c1,c2(t+1) ----
#pragma unroll
    for (int mf = 0; mf < 4; ++mf)
#pragma unroll
      for (int kk = 0; kk < 2; ++kk) {
        int r = wm * 64 + mf * 16 + qlane;
        af[mf][kk] = *(const short8*)&bp[r * 64 + ((kk * 4 + kgrp) ^ (r & 7)) * 8];
      }
#pragma unroll
    for (int nf = 0; nf < 2; ++nf)
#pragma unroll
      for (int kk = 0; kk < 2; ++kk) {
        int r = wn * 96 + nf * 16 + qlane;
        bf[nf][kk] = *(const short8*)&bp[AU + r * 64 + ((kk * 4 + kgrp) ^ (r & 7)) * 8];
      }
    if (t + 1 < NT) { stgB(t + 1, 2); stgB(t + 1, 3); stgB(t + 1, 4); stgB(t + 1, 5); }
    wgbar();
    asm volatile("s_waitcnt lgkmcnt(0)" ::: "memory");
    __builtin_amdgcn_s_setprio(1);
#pragma unroll
    for (int mf = 0; mf < 4; ++mf)
#pragma unroll
      for (int nf = 0; nf < 2; ++nf)
#pragma unroll
        for (int kk = 0; kk < 2; ++kk)
          acc[mf][nf] = __builtin_amdgcn_mfma_f32_16x16x32_bf16(
              af[mf][kk], bf[nf][kk], acc[mf][nf], 0, 0, 0);
    __builtin_amdgcn_s_setprio(0);
    wgbar();

    // ---- P2: read B nf2-3 (4); stage A(t+2) ----
#pragma unroll
    for (int nf = 0; nf < 2; ++nf)
#pragma unroll
      for (int kk = 0; kk < 2; ++kk) {
        int r = wn * 96 + (nf + 2) * 16 + qlane;
        bf[nf][kk] = *(const short8*)&bp[AU + r * 64 + ((kk * 4 + kgrp) ^ (r & 7)) * 8];
      }
    if (t + 2 < NT) { stgA(t + 2, 0); stgA(t + 2, 1); stgA(t + 2, 2); stgA(t + 2, 3); }
    wgbar();
    asm volatile("s_waitcnt lgkmcnt(0)" ::: "memory");
    __builtin_amdgcn_s_setprio(1);
#pragma unroll
    for (int mf = 0; mf < 4; ++mf)
#pragma unroll
      for (int nf = 0; nf < 2; ++nf)
#pragma unroll
        for (int kk = 0; kk < 2; ++kk)
          acc[mf][nf + 2] = __builtin_amdgcn_mfma_f32_16x16x32_bf16(
              af[mf][kk], bf[nf][kk], acc[mf][nf + 2], 0, 0, 0);
    __builtin_amdgcn_s_setprio(0);
    wgbar();

    // ---- P3: read B nf4-5 (4); stage B-c0(t+2); gate vmcnt ----
#pragma unroll
    for (int nf = 0; nf < 2; ++nf)
#pragma unroll
      for (int kk = 0; kk < 2; ++kk) {
        int r = wn * 96 + (nf + 4) * 16 + qlane;
        bf[nf][kk] = *(const short8*)&bp[AU + r * 64 + ((kk * 4 + kgrp) ^ (r & 7)) * 8];
      }
    if (t + 2 < NT) { stgB(t + 2, 0); stgB(t + 2, 1); }
    wgbar();
    asm volatile("s_waitcnt lgkmcnt(0)" ::: "memory");
    __builtin_amdgcn_s_setprio(1);
#pragma unroll
    for (int mf = 0; mf < 4; ++mf)
#pragma unroll
      for (int nf = 0; nf < 2; ++nf)
#pragma unroll
        for (int kk = 0; kk < 2; ++kk)
          acc[mf][nf + 4] = __builtin_amdgcn_mfma_f32_16x16x32_bf16(
              af[mf][kk], bf[nf][kk], acc[mf][nf + 4], 0, 0, 0);
    __builtin_amdgcn_s_setprio(0);
    if (t + 2 < NT)      asm volatile("s_waitcnt vmcnt(6)" ::: "memory");
    else if (t + 1 < NT) asm volatile("s_waitcnt vmcnt(0)" ::: "memory");
    if (t + 1 < NT) wgbar();
  }

  // epilogue
#pragma unroll
  for (int nf = 0; nf < 6; ++nf) {
    int col = bn * 192 + wn * 96 + nf * 16 + qlane;
    float bv = bias[col];
#pragma unroll
    for (int mf = 0; mf < 4; ++mf) {
      int row0 = bm * 128 + wm * 64 + mf * 16 + kgrp * 4;
#pragma unroll
      for (int r = 0; r < 4; ++r)
        C[(size_t)(row0 + r) * N + col] = f2bf(acc[mf][nf][r] + bv);
    }
  }
}

// ---------------- GEMM2: 2-phase ring-2 (round-6, proven) + super-tile ----
__global__ __launch_bounds__(256, 2) void gemm_k2(
    const u16* __restrict__ A, const u16* __restrict__ Bt,
    const float* __restrict__ bias, float* __restrict__ C) {
  constexpr int K = 1024, NT = 16, N = 1024;
  constexpr int AU = 128 * 64;            // 8192 u16
  constexpr int SLAB = 256 * 64;          // 16384 u16 (32 KiB)
  __shared__ __align__(16) u16 smem[2 * SLAB];

  const int tid = threadIdx.x;
  const int wave = tid >> 6, lane = tid & 63;
  const int qlane = lane & 15, kgrp = lane >> 4;
  const int wm = wave >> 1, wn = wave & 1;
  const int wg = blockIdx.x;
  const int xcd = wg & 7, local = wg >> 3;   // 64 blocks per XCD
  const int bm = (xcd >> 1) * 16 + (local >> 2);   // 64 bm rows
  const int bn = (xcd & 1) * 4 + (local & 3);      // 8 bn cols

  const int srow = tid >> 3;
  const int sslot = (tid & 7) ^ (srow & 7);
  uint32_t gA[4], gB[4];
#pragma unroll
  for (int u = 0; u < 4; ++u) {
    gA[u] = (uint32_t)((bm * 128 + u * 32 + srow) * K + sslot * 8);
    gB[u] = (uint32_t)((bn * 128 + u * 32 + srow) * K + sslot * 8);
  }
  auto stgA = [&](int t, int u) {
    gload16(A + (size_t)gA[u] + t * 64, &smem[(t & 1) * SLAB + u * 2048 + tid * 8]);
  };
  auto stgB = [&](int t, int u) {
    gload16(Bt + (size_t)gB[u] + t * 64, &smem[(t & 1) * SLAB + AU + u * 2048 + tid * 8]);
  };

  int aaddr[4], baddr[4];
#pragma unroll
  for (int f = 0; f < 4; ++f) {
    aaddr[f] = (wm * 64 + f * 16 + qlane) * 64;
    baddr[f] = AU + (wn * 64 + f * 16 + qlane) * 64;
  }
  const int arow7 = (wm * 64 + qlane) & 7;
  const int brow7 = (wn * 64 + qlane) & 7;

  f32x4 acc[4][4] = {};
  short8 af[4][2], bf[2][2];

#pragma unroll
  for (int u = 0; u < 4; ++u) stgA(0, u);
#pragma unroll
  for (int u = 0; u < 4; ++u) stgB(0, u);
#pragma unroll
  for (int u = 0; u < 4; ++u) stgA(1, u);
  stgB(1, 0); stgB(1, 2);
  asm volatile("s_waitcnt vmcnt(6)" ::: "memory");
  wgbar();

  for (int t = 0; t < NT; ++t) {
    const u16* bp = &smem[(t & 1) * SLAB];

    // ---- P1 ----
#pragma unroll
    for (int mf = 0; mf < 4; ++mf)
#pragma unroll
      for (int kk = 0; kk < 2; ++kk)
        af[mf][kk] = *(const short8*)&bp[aaddr[mf] + (((kk * 4 + kgrp) ^ arow7) * 8)];
#pragma unroll
    for (int nf = 0; nf < 2; ++nf)
#pragma unroll
      for (int kk = 0; kk < 2; ++kk)
        bf[nf][kk] = *(const short8*)&bp[baddr[nf] + (((kk * 4 + kgrp) ^ brow7) * 8)];
    if (t + 1 < NT) { stgB(t + 1, 1); stgB(t + 1, 3); }
    wgbar();
    asm volatile("s_waitcnt lgkmcnt(0)" ::: "memory");
    __builtin_amdgcn_s_setprio(1);
#pragma unroll
    for (int mf = 0; mf < 4; ++mf)
#pragma unroll
      for (int nf = 0; nf < 2; ++nf)
#pragma unroll
        for (int kk = 0; kk < 2; ++kk)
          acc[mf][nf] = __builtin_amdgcn_mfma_f32_16x16x32_bf16(
              af[mf][kk], bf[nf][kk], acc[mf][nf], 0, 0, 0);
    __builtin_amdgcn_s_setprio(0);
    wgbar();

    // ---- P2 ----
#pragma unroll
    for (int nf = 0; nf < 2; ++nf)
#pragma unroll
      for (int kk = 0; kk < 2; ++kk)
        bf[nf][kk] = *(const short8*)&bp[baddr[nf + 2] + (((kk * 4 + kgrp) ^ brow7) * 8)];
    if (t + 2 < NT) {
      stgA(t + 2, 0); stgA(t + 2, 1); stgA(t + 2, 2); stgA(t + 2, 3);
      stgB(t + 2, 0); stgB(t + 2, 2);
    }
    wgbar();
    asm volatile("s_waitcnt lgkmcnt(0)" ::: "memory");
    __builtin_amdgcn_s_setprio(1);
#pragma unroll
    for (int mf = 0; mf < 4; ++mf)
#pragma unroll
      for (int nf = 0; nf < 2; ++nf)
#pragma unroll
        for (int kk = 0; kk < 2; ++kk)
          acc[mf][nf + 2] = __builtin_amdgcn_mfma_f32_16x16x32_bf16(
              af[mf][kk], bf[nf][kk], acc[mf][nf + 2], 0, 0, 0);
    __builtin_amdgcn_s_setprio(0);
    if (t + 2 < NT)      asm volatile("s_waitcnt vmcnt(6)" ::: "memory");
    else if (t + 1 < NT) asm volatile("s_waitcnt vmcnt(0)" ::: "memory");
    if (t + 1 < NT) wgbar();
  }

#pragma unroll
  for (int nf = 0; nf < 4; ++nf) {
    int col = bn * 128 + wn * 64 + nf * 16 + qlane;
    float bv = bias[col];
#pragma unroll
    for (int mf = 0; mf < 4; ++mf) {
      int row0 = bm * 128 + wm * 64 + mf * 16 + kgrp * 4;
#pragma unroll
      for (int r = 0; r < 4; ++r)
        C[(size_t)(row0 + r) * N + col] = acc[mf][nf][r] + bv;
    }
  }
}

// ---------------- banded local attention (round-9, XCD-clustered) ---------
__global__ __launch_bounds__(256, 2) void attn_local(
    const u16* __restrict__ qkv, const int* __restrict__ amask,
    u16* __restrict__ aout) {
  __shared__ __align__(16) u16 Kl[192][72];
  __shared__ __align__(16) u16 Vt[64][200];
  __shared__ __align__(16) u16 Pl[4][32][104];

  const int tid = threadIdx.x, wave = tid >> 6, lane = tid & 63;
  const int qlane = lane & 15, kgrp = lane >> 4;
  const int rbz = blockIdx.x;
  const int bz = (rbz & 7) * 128 + (rbz >> 3);
  const int qt = bz & 15, h = (bz >> 4) & 15, b = bz >> 8;
  const int qs0 = qt * 128;
  const int jt = qs0 - 32;
  const size_t rbase = (size_t)b * S_LEN;

  {
    const int r0 = tid >> 3, c0 = (tid & 7) * 8;
#pragma unroll
    for (int p = 0; p < 6; ++p) {
      int row = p * 32 + r0;
      int j = jt + row;
      u16 kv[8], vv[8];
      if (j >= 0 && j < S_LEN) {
        const u16* kp = qkv + (rbase + j) * QKV_LD + HID + h * 64 + c0;
        *(short8*)kv = *(const short8*)kp;
        *(short8*)vv = *(const short8*)(kp + HID);
      } else {
#pragma unroll
        for (int q = 0; q < 8; ++q) { kv[q] = 0; vv[q] = 0; }
      }
      *(short8*)&Kl[row][c0] = *(short8*)kv;
#pragma unroll
      for (int q = 0; q < 8; ++q) Vt[c0 + q][row] = vv[q];
    }
  }

  short8 qf[2][2];
#pragma unroll
  for (int mf = 0; mf < 2; ++mf)
#pragma unroll
    for (int kk = 0; kk < 2; ++kk)
      qf[mf][kk] = *(const short8*)(qkv +
          (rbase + qs0 + wave * 32 + mf * 16 + qlane) * QKV_LD +
          h * 64 + kk * 32 + kgrp * 8);

  __syncthreads();

  f32x4 sc[2][6] = {};
#pragma unroll
  for (int kk = 0; kk < 2; ++kk) {
    short8 kf[6];
#pragma unroll
    for (int nf = 0; nf < 6; ++nf)
      kf[nf] = *(const short8*)&Kl[wave * 32 + nf * 16 + qlane][kk * 32 + kgrp * 8];
#pragma unroll
    for (int mf = 0; mf < 2; ++mf)
#pragma unroll
      for (int nf = 0; nf < 6; ++nf)
        sc[mf][nf] = __builtin_amdgcn_mfma_f32_16x16x32_bf16(
            qf[mf][kk], kf[nf], sc[mf][nf], 0, 0, 0);
  }

  int jcol[6], mv[6];
#pragma unroll
  for (int nf = 0; nf < 6; ++nf) {
    int j = jt + wave * 32 + nf * 16 + qlane;
    jcol[nf] = j;
    mv[nf] = (j >= 0 && j < S_LEN) ? amask[rbase + j] : 0;
  }

  float inv[2][4];
#pragma unroll
  for (int mf = 0; mf < 2; ++mf) {
    const int irow0 = qs0 + wave * 32 + mf * 16 + kgrp * 4;
    float mx[4] = {-1e30f, -1e30f, -1e30f, -1e30f};
#pragma unroll
    for (int r = 0; r < 4; ++r) {
      int i = irow0 + r;
#pragma unroll
      for (int nf = 0; nf < 6; ++nf) {
        int d = i - jcol[nf];
        if (mv[nf] && d >= -32 && d <= 32) mx[r] = fmaxf(mx[r], sc[mf][nf][r]);
      }
    }
#pragma unroll
    for (int m = 1; m < 16; m <<= 1)
#pragma unroll
      for (int r = 0; r < 4; ++r)
        mx[r] = fmaxf(mx[r], __shfl_xor(mx[r], m));
    float sm[4] = {0.f, 0.f, 0.f, 0.f};
#pragma unroll
    for (int r = 0; r < 4; ++r) {
      int i = irow0 + r;
#pragma unroll
      for (int nf = 0; nf < 6; ++nf) {
        int d = i - jcol[nf];
        bool val = mv[nf] && d >= -32 && d <= 32;
        float p = val ? __expf((sc[mf][nf][r] - mx[r]) * 0.125f) : 0.f;
        sc[mf][nf][r] = p;
        sm[r] += p;
      }
    }
#pragma unroll
    for (int m = 1; m < 16; m <<= 1)
#pragma unroll
      for (int r = 0; r < 4; ++r)
        sm[r] += __shfl_xor(sm[r], m);
#pragma unroll
    for (int r = 0; r < 4; ++r)
      inv[mf][r] = sm[r] > 0.f ? 1.f / sm[r] : 0.f;
#pragma unroll
    for (int nf = 0; nf < 6; ++nf)
#pragma unroll
      for (int r = 0; r < 4; ++r)
        Pl[wave][mf * 16 + kgrp * 4 + r][nf * 16 + qlane] = f2bf(sc[mf][nf][r]);
  }
  __syncthreads();

  f32x4 oc[2][4] = {};
#pragma unroll
  for (int ks = 0; ks < 3; ++ks) {
    short8 pa[2], vb[4];
#pragma unroll
    for (int mf = 0; mf < 2; ++mf)
      pa[mf] = *(const short8*)&Pl[wave][mf * 16 + qlane][ks * 32 + kgrp * 8];
#pragma unroll
    for (int nf = 0; nf < 4; ++nf)
      vb[nf] = *(const short8*)&Vt[nf * 16 + qlane][wave * 32 + ks * 32 + kgrp * 8];
#pragma unroll
    for (int mf = 0; mf < 2; ++mf)
#pragma unroll
      for (int nf = 0; nf < 4; ++nf)
        oc[mf][nf] = __builtin_amdgcn_mfma_f32_16x16x32_bf16(
            pa[mf], vb[nf], oc[mf][nf], 0, 0, 0);
  }

#pragma unroll
  for (int mf = 0; mf < 2; ++mf)
#pragma unroll
    for (int nf = 0; nf < 4; ++nf)
#pragma unroll
      for (int r = 0; r < 4; ++r) {
        size_t row = rbase + qs0 + wave * 32 + mf * 16 + kgrp * 4 + r;
        aout[row * HID + h * 64 + nf * 16 + qlane] =
            f2bf(oc[mf][nf][r] * inv[mf][r]);
      }
}

// ---------------- launch ----------------
extern "C" void kernel_launch(void* const* d_in, const int* in_sizes, int n_in,
                              void* d_out, int out_size, void* d_ws, size_t ws_size,
                              hipStream_t stream) {
  const float* x  = (const float*)d_in[0];
  const int* amask = (const int*)d_in[1];
  const float* Wq = (const float*)d_in[2];
  const float* bq = (const float*)d_in[3];
  const float* Wk = (const float*)d_in[4];
  const float* bk = (const float*)d_in[5];
  const float* Wv = (const float*)d_in[6];
  const float* bv = (const float*)d_in[7];
  const float* Wo = (const float*)d_in[8];
  const float* bo = (const float*)d_in[9];
  float* out = (float*)d_out;

  char* w = (char*)d_ws;
  u16* xb    = (u16*)w;   w += (size_t)M_ROWS * HID * 2;
  u16* wqkvt = (u16*)w;   w += (size_t)3072 * 1024 * 2;
  u16* wot   = (u16*)w;   w += (size_t)1024 * 1024 * 2;
  float* bqkv = (float*)w; w += 3072 * 4 + 256;
  u16* qkv   = (u16*)w;   w += (size_t)M_ROWS * 3072 * 2;
  u16* aout  = (u16*)w;   w += (size_t)M_ROWS * HID * 2;

  prep<<<8193, 256, 0, stream>>>(x, xb, bq, bk, bv, bqkv,
                                 Wq, Wk, Wv, Wo, wqkvt, wot);
  gemm_k1<<<1024, 256, 0, stream>>>(xb, wqkvt, bqkv, qkv);
  attn_local<<<1024, 256, 0, stream>>>(qkv, amask, aout);
  gemm_k2<<<512, 256, 0, stream>>>(aout, wot, bo, out);
}